// Round 18
// baseline (41.299 us; speedup 1.0000x reference)
//
#include <hip/hip_runtime.h>
#include <hip/hip_bf16.h>
#include <cstdint>
#include <cstddef>

#define B_ 8
#define T_ 2048
#define E_ 1024
#define D_ 64

typedef __attribute__((ext_vector_type(8))) short bf16x8;
typedef __attribute__((ext_vector_type(4))) float f32x4;
typedef __attribute__((ext_vector_type(16))) float f32x16;
typedef __attribute__((ext_vector_type(4))) unsigned short u16x4;

#define QSCALE 0.1803368801111204f  // 0.125 * log2(e)

__device__ __forceinline__ short f2bf(float f){
    __hip_bfloat16 h = __float2bfloat16(f);
    return *reinterpret_cast<short*>(&h);
}

__device__ __forceinline__ bf16x8 cvt8v(const f32x4 a, const f32x4 b){
    bf16x8 r;
    r[0]=f2bf(a[0]); r[1]=f2bf(a[1]); r[2]=f2bf(a[2]); r[3]=f2bf(a[3]);
    r[4]=f2bf(b[0]); r[5]=f2bf(b[1]); r[6]=f2bf(b[2]); r[7]=f2bf(b[3]);
    return r;
}

// ---------- W -> MFMA-fragment-linear layout (unchanged) ----------
__global__ __launch_bounds__(256) void wconv_kernel(
    const float* __restrict__ Wq, const float* __restrict__ Wk,
    const float* __restrict__ Wv, __hip_bfloat16* __restrict__ Wfrag)
{
    const int g = blockIdx.x*256 + threadIdx.x;   // [0, 24576)
    const int l = g & 63;
    const int ntg = (g >> 6) % 6;
    const int cg = g / 384;
    const int n = ntg*32 + (l & 31);
    const int m = n >> 6;
    const int ncol = n & 63;
    const float* W = (m==0) ? Wq : (m==1) ? Wk : Wv;
    const float sc = (m==0) ? QSCALE : 1.0f;
    const int k0 = cg*16 + (l>>5)*8;
    bf16x8 r;
    #pragma unroll
    for (int j=0;j<8;++j)
        r[j] = f2bf(W[(size_t)(k0+j)*64 + ncol] * sc);
    *reinterpret_cast<bf16x8*>(Wfrag + (size_t)g*8) = r;
}

// ---------- QKV projection v6 (byte-identical to R14/R17 known-best) ----------
__global__ __launch_bounds__(384, 3) void proj_kernel(
    const float* __restrict__ x, const __hip_bfloat16* __restrict__ Wfrag,
    __hip_bfloat16* __restrict__ Qfrag, __hip_bfloat16* __restrict__ Kfrag,
    __hip_bfloat16* __restrict__ Vfrag)
{
    __shared__ __align__(16) unsigned short xs[2][32*64];
    __shared__ float vtQ[32*65];
    __shared__ float vtK[32*65];
    __shared__ float vtV[32*65];
    const int tid = threadIdx.x;
    const int w = tid>>6, l = tid&63;
    const int l31 = l&31, kg = l>>5;
    const float* xp = x + (size_t)blockIdx.x*32*E_;

    f32x16 acc;
    #pragma unroll
    for (int j=0;j<16;++j) acc[j]=0.f;

    const bf16x8* Wfp = reinterpret_cast<const bf16x8*>(Wfrag);

    bf16x8 btA[4], btB[4];
    #pragma unroll
    for (int c=0;c<4;++c)
        btA[c] = Wfp[(size_t)(((0*4+c)*6 + w)*64 + l)];

    const int srow = tid>>3, sc8 = tid&7;

    if (tid < 256){
        f32x4 v0 = *reinterpret_cast<const f32x4*>(xp + (size_t)srow*E_ + sc8*8);
        f32x4 v1 = *reinterpret_cast<const f32x4*>(xp + (size_t)srow*E_ + sc8*8 + 4);
        *reinterpret_cast<bf16x8*>((char*)&xs[0][0] + srow*128 + ((sc8*16) ^ ((srow&7)<<4))) = cvt8v(v0, v1);
    }
    __syncthreads();

#define PSTEP(T, BC, BN)                                                       \
    {                                                                          \
        const int t = (T);                                                     \
        if (t+1 < 16){                                                         \
            _Pragma("unroll")                                                  \
            for (int c=0;c<4;++c)                                              \
                BN[c] = Wfp[(size_t)((((t+1)*4+c)*6 + w)*64 + l)];             \
        }                                                                      \
        f32x4 xa0, xa1;                                                        \
        if (t+1 < 16 && tid < 256){                                            \
            xa0 = *reinterpret_cast<const f32x4*>(xp + (size_t)srow*E_ + (t+1)*64 + sc8*8);     \
            xa1 = *reinterpret_cast<const f32x4*>(xp + (size_t)srow*E_ + (t+1)*64 + sc8*8 + 4); \
        }                                                                      \
        const char* xb = (const char*)&xs[t&1][0];                             \
        _Pragma("unroll")                                                      \
        for (int c=0;c<4;++c){                                                 \
            bf16x8 af = *reinterpret_cast<const bf16x8*>(xb + l31*128 + (((c*32 + kg*16)) ^ ((l31&7)<<4))); \
            acc = __builtin_amdgcn_mfma_f32_32x32x16_bf16(af, BC[c], acc, 0,0,0); \
        }                                                                      \
        if (t+1 < 16){                                                         \
            if (tid < 256)                                                     \
                *reinterpret_cast<bf16x8*>((char*)&xs[(t+1)&1][0] + srow*128 + ((sc8*16) ^ ((srow&7)<<4))) = cvt8v(xa0, xa1); \
            __syncthreads();                                                   \
        }                                                                      \
    }

    for (int t2=0; t2<8; ++t2){
        PSTEP(2*t2,   btA, btB)
        PSTEP(2*t2+1, btB, btA)
    }
#undef PSTEP

    {
        float* vtX = (w<2) ? vtQ : (w<4) ? vtK : vtV;
        const int col = (w&1)*32 + l31;
        #pragma unroll
        for (int reg=0; reg<16; ++reg){
            const int mr = (reg&3) + 8*(reg>>2) + 4*kg;
            vtX[mr*65 + col] = acc[reg];
        }
    }
    __syncthreads();
    if (tid < 256){
        const int q = blockIdx.x, b = q>>6, q63 = q&63, t = q63>>1;
        const int su  = (tid>>7)&1, ksw = (tid>>6)&1, lw = tid&63;
        const int lw15 = lw&15, lwg = lw>>4;
        {
            f32x4 a0, a1;
            #pragma unroll
            for (int j=0;j<4;++j) a0[j] = vtQ[(su*16+lw15)*65 + ksw*32 + lwg*8 + j];
            #pragma unroll
            for (int j=0;j<4;++j) a1[j] = vtQ[(su*16+lw15)*65 + ksw*32 + lwg*8 + 4 + j];
            const size_t gi = ((size_t)(b*128 + 2*q63 + su)*2 + ksw)*64 + lw;
            *reinterpret_cast<bf16x8*>(Qfrag + gi*8) = cvt8v(a0, a1);
        }
        {
            f32x4 a0, a1;
            #pragma unroll
            for (int j=0;j<4;++j) a0[j] = vtK[(su*16+lw15)*65 + ksw*32 + lwg*8 + j];
            #pragma unroll
            for (int j=0;j<4;++j) a1[j] = vtK[(su*16+lw15)*65 + ksw*32 + lwg*8 + 4 + j];
            const int nt = (q&1)*2 + su;
            const size_t gi = (((size_t)(b*32 + t)*4 + nt)*2 + ksw)*64 + lw;
            *reinterpret_cast<bf16x8*>(Kfrag + gi*8) = cvt8v(a0, a1);
        }
        {
            const int dt = tid>>6;
            bf16x8 pk;
            #pragma unroll
            for (int j=0;j<8;++j)
                pk[j] = f2bf(vtV[(lwg*8+j)*65 + dt*16 + lw15]);
            const size_t gi = (((size_t)(b*32 + t)*4 + dt)*2 + (q&1))*64 + lw;
            *reinterpret_cast<bf16x8*>(Vfrag + gi*8) = pk;
        }
    }
}

// ---------- flash attention v11: v10 + next-unit kf prefetch (register-reuse pipeline) ----------
__global__ __launch_bounds__(256, 4) void fattn_kernel(
    const __hip_bfloat16* __restrict__ Qfrag, const __hip_bfloat16* __restrict__ Kfrag,
    const __hip_bfloat16* __restrict__ Vfrag, float* __restrict__ out)
{
    __shared__ __align__(16) unsigned short Pl[4][1024];
    __shared__ float Morg[4][16];
    __shared__ float Lorg[4][64];
    __shared__ __align__(16) float Oorg[4][16*64];

    const int tid = threadIdx.x;
    const int w = tid>>6, l = tid&63;
    const int l15 = l&15, lg = l>>4;

    const int b = blockIdx.x & 7;
    const int g = blockIdx.x >> 8;
    const int r = (blockIdx.x >> 3) & 31;
    const int s = (g==0) ? (127 - r) : (g==1) ? (64 + r) : (g==2) ? (63 - r) : r;
    const int n = (s>>2) + 1;
    const size_t batchoff = (size_t)b * T_ * 64;

    const bf16x8* qfp = reinterpret_cast<const bf16x8*>(Qfrag);
    const bf16x8* kfp = reinterpret_cast<const bf16x8*>(Kfrag);
    const bf16x8* vfp = reinterpret_cast<const bf16x8*>(Vfrag);
    char* pw = (char*)&Pl[w][0];

    const int qrow = s*16 + l15;
    const bf16x8 qf0 = qfp[(size_t)((b*128 + s)*2 + 0)*64 + l];
    const bf16x8 qf1 = qfp[(size_t)((b*128 + s)*2 + 1)*64 + l];

    f32x4 o[4];
    #pragma unroll
    for (int i=0;i<4;++i) o[i] = (f32x4){0.f,0.f,0.f,0.f};
    float mrun = -1e30f, lrun = 0.f;

    // prologue: kf loads for the first unit
    bf16x8 kf[8];
    if (w < n){
        #pragma unroll
        for (int ks=0;ks<2;++ks)
            #pragma unroll
            for (int nt=0;nt<4;++nt)
                kf[ks*4+nt] = kfp[(size_t)(((b*32 + w)*4 + nt)*2 + ks)*64 + l];
    }

    for (int kvt = w; kvt < n; kvt += 4){
        // ---- QK^T: kf already in flight / resident ----
        f32x4 s4[4];
        #pragma unroll
        for (int nt=0;nt<4;++nt) s4[nt] = (f32x4){0.f,0.f,0.f,0.f};
        __builtin_amdgcn_s_setprio(1);
        #pragma unroll
        for (int ks=0;ks<2;++ks){
            const bf16x8 qf = ks ? qf1 : qf0;
            #pragma unroll
            for (int nt=0;nt<4;++nt)
                s4[nt] = __builtin_amdgcn_mfma_f32_16x16x32_bf16(kf[ks*4+nt], qf, s4[nt], 0,0,0);
        }
        __builtin_amdgcn_s_setprio(0);

        // ---- vf loads: land under softmax + P-write ----
        bf16x8 vf[8];
        #pragma unroll
        for (int ks=0;ks<2;++ks)
            #pragma unroll
            for (int nt=0;nt<4;++nt)
                vf[ks*4+nt] = vfp[(size_t)(((b*32 + kvt)*4 + nt)*2 + ks)*64 + l];

        // ---- next-unit kf prefetch into the SAME registers (dead after QK issue) ----
        if (kvt + 4 < n){
            #pragma unroll
            for (int ks=0;ks<2;++ks)
                #pragma unroll
                for (int nt=0;nt<4;++nt)
                    kf[ks*4+nt] = kfp[(size_t)(((b*32 + kvt + 4)*4 + nt)*2 + ks)*64 + l];
        }

        if (kvt == n-1){
            const int kv0 = kvt*64;
            #pragma unroll
            for (int nt=0;nt<4;++nt)
                #pragma unroll
                for (int rr=0;rr<4;++rr){
                    const int kv = kv0 + nt*16 + lg*4 + rr;
                    if (kv > qrow) s4[nt][rr] = -1e30f;
                }
        }

        float pmLoc;
        {
            float m0 = fmaxf(fmaxf(s4[0][0],s4[0][1]), fmaxf(s4[0][2],s4[0][3]));
            float m1 = fmaxf(fmaxf(s4[1][0],s4[1][1]), fmaxf(s4[1][2],s4[1][3]));
            float m2 = fmaxf(fmaxf(s4[2][0],s4[2][1]), fmaxf(s4[2][2],s4[2][3]));
            float m3 = fmaxf(fmaxf(s4[3][0],s4[3][1]), fmaxf(s4[3][2],s4[3][3]));
            pmLoc = fmaxf(fmaxf(m0,m1), fmaxf(m2,m3));
        }
        if (__any(pmLoc > mrun + 8.0f)){
            float pm = pmLoc;
            pm = fmaxf(pm, __shfl_xor(pm, 16));
            pm = fmaxf(pm, __shfl_xor(pm, 32));
            const float mn = fmaxf(mrun, pm);
            const float scl = exp2f(mrun - mn);
            mrun = mn; lrun *= scl;
            #pragma unroll
            for (int dt=0;dt<4;++dt)
                #pragma unroll
                for (int j=0;j<4;++j) o[dt][j] *= scl;
        }
        float rs = 0.f;
        #pragma unroll
        for (int nt=0;nt<4;++nt)
            #pragma unroll
            for (int rr=0;rr<4;++rr){
                const float pv = exp2f(s4[nt][rr] - mrun);
                s4[nt][rr] = pv; rs += pv;
            }
        lrun += rs;

        #pragma unroll
        for (int nt=0;nt<4;++nt){
            u16x4 pk;
            #pragma unroll
            for (int rr=0;rr<4;++rr) pk[rr] = (unsigned short)f2bf(s4[nt][rr]);
            *reinterpret_cast<u16x4*>(pw + l15*128 + ((nt*32 + lg*8) ^ ((l15&7)<<4))) = pk;
        }
        __builtin_amdgcn_s_setprio(1);
        #pragma unroll
        for (int ks=0;ks<2;++ks){
            bf16x8 pf = *reinterpret_cast<const bf16x8*>(pw + l15*128 + ((ks*64 + lg*16) ^ ((l15&7)<<4)));
            #pragma unroll
            for (int dt=0;dt<4;++dt)
                o[dt] = __builtin_amdgcn_mfma_f32_16x16x32_bf16(vf[ks*4+dt], pf, o[dt], 0,0,0);
        }
        __builtin_amdgcn_s_setprio(0);
    }

    #pragma unroll
    for (int dt=0;dt<4;++dt)
        *reinterpret_cast<f32x4*>(&Oorg[w][l15*64 + dt*16 + lg*4]) = o[dt];
    Lorg[w][l] = lrun;
    if (lg == 0) Morg[w][l15] = mrun;
    __syncthreads();
    {
        const int q = tid >> 4, dg = tid & 15;
        const float m0=Morg[0][q], m1=Morg[1][q], m2=Morg[2][q], m3=Morg[3][q];
        const float M = fmaxf(fmaxf(m0,m1), fmaxf(m2,m3));
        const float a0=exp2f(m0-M), a1=exp2f(m1-M), a2=exp2f(m2-M), a3=exp2f(m3-M);
        float L = 0.f;
        #pragma unroll
        for (int lgg=0; lgg<4; ++lgg){
            L += a0*Lorg[0][lgg*16+q] + a1*Lorg[1][lgg*16+q]
               + a2*Lorg[2][lgg*16+q] + a3*Lorg[3][lgg*16+q];
        }
        const float inv = 1.0f / L;
        float* op = out + batchoff + (size_t)(s*16 + q)*64 + dg*4;
        #pragma unroll
        for (int j=0;j<4;++j){
            const float v = a0*Oorg[0][q*64+dg*4+j] + a1*Oorg[1][q*64+dg*4+j]
                          + a2*Oorg[2][q*64+dg*4+j] + a3*Oorg[3][q*64+dg*4+j];
            op[j] = v * inv;
        }
    }
}

extern "C" void kernel_launch(void* const* d_in, const int* in_sizes, int n_in,
                              void* d_out, int out_size, void* d_ws, size_t ws_size,
                              hipStream_t stream) {
    const float* x  = (const float*)d_in[0];
    const float* Wq = (const float*)d_in[1];
    const float* Wk = (const float*)d_in[2];
    const float* Wv = (const float*)d_in[3];
    float* out = (float*)d_out;

    const size_t NTOK = (size_t)B_*T_*64;
    __hip_bfloat16* Wfrag = (__hip_bfloat16*)d_ws;
    __hip_bfloat16* Qfrag = Wfrag + (size_t)24576*8;
    __hip_bfloat16* Kfrag = Qfrag + NTOK;
    __hip_bfloat16* Vfrag = Kfrag + NTOK;

    wconv_kernel<<<96, 256, 0, stream>>>(Wq, Wk, Wv, Wfrag);
    proj_kernel<<<512, 384, 0, stream>>>(x, Wfrag, Qfrag, Kfrag, Vfrag);
    fattn_kernel<<<1024, 256, 0, stream>>>(Qfrag, Kfrag, Vfrag, out);
}

// Round 19
// 36.940 us; speedup vs baseline: 1.1180x; 1.1180x over previous
//
#include <hip/hip_runtime.h>
#include <hip/hip_bf16.h>
#include <cstdint>
#include <cstddef>

#define B_ 8
#define T_ 2048
#define E_ 1024
#define D_ 64

typedef __attribute__((ext_vector_type(8))) short bf16x8;
typedef __attribute__((ext_vector_type(4))) float f32x4;
typedef __attribute__((ext_vector_type(16))) float f32x16;
typedef __attribute__((ext_vector_type(4))) unsigned short u16x4;

#define QSCALE 0.1803368801111204f  // 0.125 * log2(e)

__device__ __forceinline__ short f2bf(float f){
    __hip_bfloat16 h = __float2bfloat16(f);
    return *reinterpret_cast<short*>(&h);
}

__device__ __forceinline__ bf16x8 cvt8v(const f32x4 a, const f32x4 b){
    bf16x8 r;
    r[0]=f2bf(a[0]); r[1]=f2bf(a[1]); r[2]=f2bf(a[2]); r[3]=f2bf(a[3]);
    r[4]=f2bf(b[0]); r[5]=f2bf(b[1]); r[6]=f2bf(b[2]); r[7]=f2bf(b[3]);
    return r;
}

// ---------- W -> MFMA-fragment-linear layout ----------
__global__ __launch_bounds__(256) void wconv_kernel(
    const float* __restrict__ Wq, const float* __restrict__ Wk,
    const float* __restrict__ Wv, __hip_bfloat16* __restrict__ Wfrag)
{
    const int g = blockIdx.x*256 + threadIdx.x;   // [0, 24576)
    const int l = g & 63;
    const int ntg = (g >> 6) % 6;
    const int cg = g / 384;
    const int n = ntg*32 + (l & 31);
    const int m = n >> 6;
    const int ncol = n & 63;
    const float* W = (m==0) ? Wq : (m==1) ? Wk : Wv;
    const float sc = (m==0) ? QSCALE : 1.0f;
    const int k0 = cg*16 + (l>>5)*8;
    bf16x8 r;
    #pragma unroll
    for (int j=0;j<8;++j)
        r[j] = f2bf(W[(size_t)(k0+j)*64 + ncol] * sc);
    *reinterpret_cast<bf16x8*>(Wfrag + (size_t)g*8) = r;
}

// ---------- QKV projection v6 (R14/R17 known-best) ----------
__global__ __launch_bounds__(384, 3) void proj_kernel(
    const float* __restrict__ x, const __hip_bfloat16* __restrict__ Wfrag,
    __hip_bfloat16* __restrict__ Qfrag, __hip_bfloat16* __restrict__ Kfrag,
    __hip_bfloat16* __restrict__ Vfrag)
{
    __shared__ __align__(16) unsigned short xs[2][32*64];
    __shared__ float vtQ[32*65];
    __shared__ float vtK[32*65];
    __shared__ float vtV[32*65];
    const int tid = threadIdx.x;
    const int w = tid>>6, l = tid&63;
    const int l31 = l&31, kg = l>>5;
    const float* xp = x + (size_t)blockIdx.x*32*E_;

    f32x16 acc;
    #pragma unroll
    for (int j=0;j<16;++j) acc[j]=0.f;

    const bf16x8* Wfp = reinterpret_cast<const bf16x8*>(Wfrag);

    bf16x8 btA[4], btB[4];
    #pragma unroll
    for (int c=0;c<4;++c)
        btA[c] = Wfp[(size_t)(((0*4+c)*6 + w)*64 + l)];

    const int srow = tid>>3, sc8 = tid&7;

    if (tid < 256){
        f32x4 v0 = *reinterpret_cast<const f32x4*>(xp + (size_t)srow*E_ + sc8*8);
        f32x4 v1 = *reinterpret_cast<const f32x4*>(xp + (size_t)srow*E_ + sc8*8 + 4);
        *reinterpret_cast<bf16x8*>((char*)&xs[0][0] + srow*128 + ((sc8*16) ^ ((srow&7)<<4))) = cvt8v(v0, v1);
    }
    __syncthreads();

#define PSTEP(T, BC, BN)                                                       \
    {                                                                          \
        const int t = (T);                                                     \
        if (t+1 < 16){                                                         \
            _Pragma("unroll")                                                  \
            for (int c=0;c<4;++c)                                              \
                BN[c] = Wfp[(size_t)((((t+1)*4+c)*6 + w)*64 + l)];             \
        }                                                                      \
        f32x4 xa0, xa1;                                                        \
        if (t+1 < 16 && tid < 256){                                            \
            xa0 = *reinterpret_cast<const f32x4*>(xp + (size_t)srow*E_ + (t+1)*64 + sc8*8);     \
            xa1 = *reinterpret_cast<const f32x4*>(xp + (size_t)srow*E_ + (t+1)*64 + sc8*8 + 4); \
        }                                                                      \
        const char* xb = (const char*)&xs[t&1][0];                             \
        _Pragma("unroll")                                                      \
        for (int c=0;c<4;++c){                                                 \
            bf16x8 af = *reinterpret_cast<const bf16x8*>(xb + l31*128 + (((c*32 + kg*16)) ^ ((l31&7)<<4))); \
            acc = __builtin_amdgcn_mfma_f32_32x32x16_bf16(af, BC[c], acc, 0,0,0); \
        }                                                                      \
        if (t+1 < 16){                                                         \
            if (tid < 256)                                                     \
                *reinterpret_cast<bf16x8*>((char*)&xs[(t+1)&1][0] + srow*128 + ((sc8*16) ^ ((srow&7)<<4))) = cvt8v(xa0, xa1); \
            __syncthreads();                                                   \
        }                                                                      \
    }

    for (int t2=0; t2<8; ++t2){
        PSTEP(2*t2,   btA, btB)
        PSTEP(2*t2+1, btB, btA)
    }
#undef PSTEP

    {
        float* vtX = (w<2) ? vtQ : (w<4) ? vtK : vtV;
        const int col = (w&1)*32 + l31;
        #pragma unroll
        for (int reg=0; reg<16; ++reg){
            const int mr = (reg&3) + 8*(reg>>2) + 4*kg;
            vtX[mr*65 + col] = acc[reg];
        }
    }
    __syncthreads();
    if (tid < 256){
        const int q = blockIdx.x, b = q>>6, q63 = q&63, t = q63>>1;
        const int su  = (tid>>7)&1, ksw = (tid>>6)&1, lw = tid&63;
        const int lw15 = lw&15, lwg = lw>>4;
        {
            f32x4 a0, a1;
            #pragma unroll
            for (int j=0;j<4;++j) a0[j] = vtQ[(su*16+lw15)*65 + ksw*32 + lwg*8 + j];
            #pragma unroll
            for (int j=0;j<4;++j) a1[j] = vtQ[(su*16+lw15)*65 + ksw*32 + lwg*8 + 4 + j];
            const size_t gi = ((size_t)(b*128 + 2*q63 + su)*2 + ksw)*64 + lw;
            *reinterpret_cast<bf16x8*>(Qfrag + gi*8) = cvt8v(a0, a1);
        }
        {
            f32x4 a0, a1;
            #pragma unroll
            for (int j=0;j<4;++j) a0[j] = vtK[(su*16+lw15)*65 + ksw*32 + lwg*8 + j];
            #pragma unroll
            for (int j=0;j<4;++j) a1[j] = vtK[(su*16+lw15)*65 + ksw*32 + lwg*8 + 4 + j];
            const int nt = (q&1)*2 + su;
            const size_t gi = (((size_t)(b*32 + t)*4 + nt)*2 + ksw)*64 + lw;
            *reinterpret_cast<bf16x8*>(Kfrag + gi*8) = cvt8v(a0, a1);
        }
        {
            const int dt = tid>>6;
            bf16x8 pk;
            #pragma unroll
            for (int j=0;j<8;++j)
                pk[j] = f2bf(vtV[(lwg*8+j)*65 + dt*16 + lw15]);
            const size_t gi = (((size_t)(b*32 + t)*4 + dt)*2 + (q&1))*64 + lw;
            *reinterpret_cast<bf16x8*>(Vfrag + gi*8) = pk;
        }
    }
}

// ---------- flash attention v10 (R17 known-best): kf first, vf under softmax ----------
__global__ __launch_bounds__(256, 4) void fattn_kernel(
    const __hip_bfloat16* __restrict__ Qfrag, const __hip_bfloat16* __restrict__ Kfrag,
    const __hip_bfloat16* __restrict__ Vfrag, float* __restrict__ out)
{
    __shared__ __align__(16) unsigned short Pl[4][1024];
    __shared__ float Morg[4][16];
    __shared__ float Lorg[4][64];
    __shared__ __align__(16) float Oorg[4][16*64];

    const int tid = threadIdx.x;
    const int w = tid>>6, l = tid&63;
    const int l15 = l&15, lg = l>>4;

    const int b = blockIdx.x & 7;
    const int g = blockIdx.x >> 8;
    const int r = (blockIdx.x >> 3) & 31;
    const int s = (g==0) ? (127 - r) : (g==1) ? (64 + r) : (g==2) ? (63 - r) : r;
    const int n = (s>>2) + 1;
    const size_t batchoff = (size_t)b * T_ * 64;

    const bf16x8* qfp = reinterpret_cast<const bf16x8*>(Qfrag);
    const bf16x8* kfp = reinterpret_cast<const bf16x8*>(Kfrag);
    const bf16x8* vfp = reinterpret_cast<const bf16x8*>(Vfrag);
    char* pw = (char*)&Pl[w][0];

    const int qrow = s*16 + l15;
    const bf16x8 qf0 = qfp[(size_t)((b*128 + s)*2 + 0)*64 + l];
    const bf16x8 qf1 = qfp[(size_t)((b*128 + s)*2 + 1)*64 + l];

    f32x4 o[4];
    #pragma unroll
    for (int i=0;i<4;++i) o[i] = (f32x4){0.f,0.f,0.f,0.f};
    float mrun = -1e30f, lrun = 0.f;

    for (int kvt = w; kvt < n; kvt += 4){
        bf16x8 kf[8];
        #pragma unroll
        for (int ks=0;ks<2;++ks)
            #pragma unroll
            for (int nt=0;nt<4;++nt)
                kf[ks*4+nt] = kfp[(size_t)(((b*32 + kvt)*4 + nt)*2 + ks)*64 + l];

        f32x4 s4[4];
        #pragma unroll
        for (int nt=0;nt<4;++nt) s4[nt] = (f32x4){0.f,0.f,0.f,0.f};
        __builtin_amdgcn_s_setprio(1);
        #pragma unroll
        for (int ks=0;ks<2;++ks){
            const bf16x8 qf = ks ? qf1 : qf0;
            #pragma unroll
            for (int nt=0;nt<4;++nt)
                s4[nt] = __builtin_amdgcn_mfma_f32_16x16x32_bf16(kf[ks*4+nt], qf, s4[nt], 0,0,0);
        }
        __builtin_amdgcn_s_setprio(0);

        bf16x8 vf[8];
        #pragma unroll
        for (int ks=0;ks<2;++ks)
            #pragma unroll
            for (int nt=0;nt<4;++nt)
                vf[ks*4+nt] = vfp[(size_t)(((b*32 + kvt)*4 + nt)*2 + ks)*64 + l];

        if (kvt == n-1){
            const int kv0 = kvt*64;
            #pragma unroll
            for (int nt=0;nt<4;++nt)
                #pragma unroll
                for (int rr=0;rr<4;++rr){
                    const int kv = kv0 + nt*16 + lg*4 + rr;
                    if (kv > qrow) s4[nt][rr] = -1e30f;
                }
        }

        float pmLoc;
        {
            float m0 = fmaxf(fmaxf(s4[0][0],s4[0][1]), fmaxf(s4[0][2],s4[0][3]));
            float m1 = fmaxf(fmaxf(s4[1][0],s4[1][1]), fmaxf(s4[1][2],s4[1][3]));
            float m2 = fmaxf(fmaxf(s4[2][0],s4[2][1]), fmaxf(s4[2][2],s4[2][3]));
            float m3 = fmaxf(fmaxf(s4[3][0],s4[3][1]), fmaxf(s4[3][2],s4[3][3]));
            pmLoc = fmaxf(fmaxf(m0,m1), fmaxf(m2,m3));
        }
        if (__any(pmLoc > mrun + 8.0f)){
            float pm = pmLoc;
            pm = fmaxf(pm, __shfl_xor(pm, 16));
            pm = fmaxf(pm, __shfl_xor(pm, 32));
            const float mn = fmaxf(mrun, pm);
            const float scl = exp2f(mrun - mn);
            mrun = mn; lrun *= scl;
            #pragma unroll
            for (int dt=0;dt<4;++dt)
                #pragma unroll
                for (int j=0;j<4;++j) o[dt][j] *= scl;
        }
        float rs = 0.f;
        #pragma unroll
        for (int nt=0;nt<4;++nt)
            #pragma unroll
            for (int rr=0;rr<4;++rr){
                const float pv = exp2f(s4[nt][rr] - mrun);
                s4[nt][rr] = pv; rs += pv;
            }
        lrun += rs;

        #pragma unroll
        for (int nt=0;nt<4;++nt){
            u16x4 pk;
            #pragma unroll
            for (int rr=0;rr<4;++rr) pk[rr] = (unsigned short)f2bf(s4[nt][rr]);
            *reinterpret_cast<u16x4*>(pw + l15*128 + ((nt*32 + lg*8) ^ ((l15&7)<<4))) = pk;
        }
        __builtin_amdgcn_s_setprio(1);
        #pragma unroll
        for (int ks=0;ks<2;++ks){
            bf16x8 pf = *reinterpret_cast<const bf16x8*>(pw + l15*128 + ((ks*64 + lg*16) ^ ((l15&7)<<4)));
            #pragma unroll
            for (int dt=0;dt<4;++dt)
                o[dt] = __builtin_amdgcn_mfma_f32_16x16x32_bf16(vf[ks*4+dt], pf, o[dt], 0,0,0);
        }
        __builtin_amdgcn_s_setprio(0);
    }

    #pragma unroll
    for (int dt=0;dt<4;++dt)
        *reinterpret_cast<f32x4*>(&Oorg[w][l15*64 + dt*16 + lg*4]) = o[dt];
    Lorg[w][l] = lrun;
    if (lg == 0) Morg[w][l15] = mrun;
    __syncthreads();
    {
        const int q = tid >> 4, dg = tid & 15;
        const float m0=Morg[0][q], m1=Morg[1][q], m2=Morg[2][q], m3=Morg[3][q];
        const float M = fmaxf(fmaxf(m0,m1), fmaxf(m2,m3));
        const float a0=exp2f(m0-M), a1=exp2f(m1-M), a2=exp2f(m2-M), a3=exp2f(m3-M);
        float L = 0.f;
        #pragma unroll
        for (int lgg=0; lgg<4; ++lgg){
            L += a0*Lorg[0][lgg*16+q] + a1*Lorg[1][lgg*16+q]
               + a2*Lorg[2][lgg*16+q] + a3*Lorg[3][lgg*16+q];
        }
        const float inv = 1.0f / L;
        float* op = out + batchoff + (size_t)(s*16 + q)*64 + dg*4;
        #pragma unroll
        for (int j=0;j<4;++j){
            const float v = a0*Oorg[0][q*64+dg*4+j] + a1*Oorg[1][q*64+dg*4+j]
                          + a2*Oorg[2][q*64+dg*4+j] + a3*Oorg[3][q*64+dg*4+j];
            op[j] = v * inv;
        }
    }
}

extern "C" void kernel_launch(void* const* d_in, const int* in_sizes, int n_in,
                              void* d_out, int out_size, void* d_ws, size_t ws_size,
                              hipStream_t stream) {
    const float* x  = (const float*)d_in[0];
    const float* Wq = (const float*)d_in[1];
    const float* Wk = (const float*)d_in[2];
    const float* Wv = (const float*)d_in[3];
    float* out = (float*)d_out;

    const size_t NTOK = (size_t)B_*T_*64;
    __hip_bfloat16* Wfrag = (__hip_bfloat16*)d_ws;
    __hip_bfloat16* Qfrag = Wfrag + (size_t)24576*8;
    __hip_bfloat16* Kfrag = Qfrag + NTOK;
    __hip_bfloat16* Vfrag = Kfrag + NTOK;

    wconv_kernel<<<96, 256, 0, stream>>>(Wq, Wk, Wv, Wfrag);
    proj_kernel<<<512, 384, 0, stream>>>(x, Wfrag, Qfrag, Kfrag, Vfrag);
    fattn_kernel<<<1024, 256, 0, stream>>>(Qfrag, Kfrag, Vfrag, out);
}